// Round 1
// baseline (496.058 us; speedup 1.0000x reference)
//
#include <hip/hip_runtime.h>

typedef _Float16 half8 __attribute__((ext_vector_type(8)));
typedef _Float16 half4 __attribute__((ext_vector_type(4)));
typedef float f32x4 __attribute__((ext_vector_type(4)));
typedef float f32x16 __attribute__((ext_vector_type(16)));

// ---------------- prologue: cast + retile weights to fp16 MFMA tiles --------
// Tile (nb, ks): n in [nb*32,+32), k in [ks*16,+16), 512 halfs; lane l of a
// wave reads its A-fragment at tile_base + l*8 halfs (= l*16 bytes) -> one
// coalesced 1KB load. offset within tile for (lr=n&31, kk=k&15):
//   lr*8 + (kk>>3)*256 + (kk&7)   [halfs]
__global__ void prep_weights(const float* __restrict__ W1, const float* __restrict__ W2,
                             const float* __restrict__ W3, const float* __restrict__ W4,
                             _Float16* __restrict__ wt1, _Float16* __restrict__ wt2,
                             _Float16* __restrict__ wt3, _Float16* __restrict__ w4h) {
  int idx = blockIdx.x * blockDim.x + threadIdx.x;
  if (idx < 512 * 256) {  // W1: K=256, N=512, KS=16
    int k = idx >> 9, n = idx & 511;
    int off = (((n >> 5) * 16 + (k >> 4)) << 9) + (n & 31) * 8 + (((k >> 3) & 1) << 8) + (k & 7);
    wt1[off] = (_Float16)W1[idx];
    return;
  }
  int i2 = idx - 512 * 256;
  if (i2 < 512 * 512) {  // W2: K=512, N=512, KS=32
    int k = i2 >> 9, n = i2 & 511;
    int off = (((n >> 5) * 32 + (k >> 4)) << 9) + (n & 31) * 8 + (((k >> 3) & 1) << 8) + (k & 7);
    wt2[off] = (_Float16)W2[i2];
    return;
  }
  int i3 = i2 - 512 * 512;
  if (i3 < 512 * 256) {  // W3: K=512, N=256, KS=32
    int k = i3 >> 8, n = i3 & 255;
    int off = (((n >> 5) * 32 + (k >> 4)) << 9) + (n & 31) * 8 + (((k >> 3) & 1) << 8) + (k & 7);
    wt3[off] = (_Float16)W3[i3];
    return;
  }
  int i4 = i3 - 512 * 256;
  if (i4 < 256) w4h[i4] = (_Float16)W4[i4];
}

// silu with raw v_rcp_f32 (no IEEE div sequence); ~1ulp, well within tolerance
__device__ __forceinline__ float fast_silu(float s) {
  float e = __expf(-s);
  float d = 1.0f + e;
  float r;
  asm("v_rcp_f32 %0, %1" : "=v"(r) : "v"(d));
  return s * r;
}

// ---------------- fused MLP ----------------
// Block: 64 atoms, 512 threads = 8 waves (wave = feature slice).
// FT=2, AT=2: acc = 64 AGPR, arch-VGPR ~64 -> 4 waves/SIMD; LDS 64KB
// -> 2 blocks/CU -> 16 waves/CU.
// Swizzle (R8): byte ^= (row&31)<<4 — 5-bit XOR spreads a wave's 64 lanes
// over 32 distinct 16B slots (512B bank span) -> 2 lanes/bank = conflict-
// free. The old 3-bit mask collapsed to 8 slots -> ~8-way conflict, which
// made the LDS path dominate MFMA (R7: 3.1e7 conflict cycles).
// R9 (this round): persistent blocks + anti-phase skew between the two
// resident blocks per CU so one block's epilogue (VALU/trans) overlaps the
// other's K-loop (MFMA); setprio(1) around MFMA clusters so MFMA-phase
// waves win issue arbitration (T5 — needs the role diversity the skew
// creates); L2 touch-prefetch of next tile's X.

#define MFMA(a, b, c) __builtin_amdgcn_mfma_f32_32x32x16_f16(a, b, c, 0, 0, 0)

template <int FT, int AT, int KS, int PIN, int POUT>
__device__ __forceinline__ void layer(const _Float16* __restrict__ wt,
                                      const float* __restrict__ bias,
                                      char* __restrict__ Hb,
                                      int wfeat, int lane) {
  const int lr = lane & 31;
  const int lh = lane >> 5;
  const int n0 = wfeat * (FT * 32);
  const int s0 = (lr & 31) << 4;  // row swizzle; (a*32+lr)&31 == lr&31
  const char* Bp = Hb + lr * PIN;
  const char* wp = (const char*)wt + (size_t)(wfeat * FT * KS) * 1024 + lh * 512 + lr * 16;

  f32x16 acc[FT][AT];
#pragma unroll
  for (int f = 0; f < FT; ++f)
#pragma unroll
    for (int a = 0; a < AT; ++a) acc[f][a] = (f32x16)0.0f;

  half8 Af[FT], Ag[FT], Bf[AT], Bg[AT];
#pragma unroll
  for (int f = 0; f < FT; ++f) Af[f] = *(const half8*)(wp + f * (KS * 1024));
#pragma unroll
  for (int a = 0; a < AT; ++a)
    Bf[a] = *(const half8*)(Bp + a * 32 * PIN + ((lh * 16) ^ s0));

#pragma unroll 1
  for (int ks = 0; ks < KS - 2; ks += 2) {
    // prefetch ks+1 into g-buffers
#pragma unroll
    for (int f = 0; f < FT; ++f)
      Ag[f] = *(const half8*)(wp + f * (KS * 1024) + (ks + 1) * 1024);
#pragma unroll
    for (int a = 0; a < AT; ++a)
      Bg[a] = *(const half8*)(Bp + a * 32 * PIN + (((ks + 1) * 32 + lh * 16) ^ s0));
    // compute ks
    __builtin_amdgcn_s_setprio(1);
#pragma unroll
    for (int f = 0; f < FT; ++f)
#pragma unroll
      for (int a = 0; a < AT; ++a) acc[f][a] = MFMA(Af[f], Bf[a], acc[f][a]);
    __builtin_amdgcn_s_setprio(0);
    // prefetch ks+2 into f-buffers
#pragma unroll
    for (int f = 0; f < FT; ++f)
      Af[f] = *(const half8*)(wp + f * (KS * 1024) + (ks + 2) * 1024);
#pragma unroll
    for (int a = 0; a < AT; ++a)
      Bf[a] = *(const half8*)(Bp + a * 32 * PIN + (((ks + 2) * 32 + lh * 16) ^ s0));
    // compute ks+1
    __builtin_amdgcn_s_setprio(1);
#pragma unroll
    for (int f = 0; f < FT; ++f)
#pragma unroll
      for (int a = 0; a < AT; ++a) acc[f][a] = MFMA(Ag[f], Bg[a], acc[f][a]);
    __builtin_amdgcn_s_setprio(0);
  }
  // tail: ks = KS-2 in f-buffers; prefetch KS-1; compute both
#pragma unroll
  for (int f = 0; f < FT; ++f)
    Ag[f] = *(const half8*)(wp + f * (KS * 1024) + (KS - 1) * 1024);
#pragma unroll
  for (int a = 0; a < AT; ++a)
    Bg[a] = *(const half8*)(Bp + a * 32 * PIN + ((((KS - 1) * 32) + lh * 16) ^ s0));
  __builtin_amdgcn_s_setprio(1);
#pragma unroll
  for (int f = 0; f < FT; ++f)
#pragma unroll
    for (int a = 0; a < AT; ++a) acc[f][a] = MFMA(Af[f], Bf[a], acc[f][a]);
#pragma unroll
  for (int f = 0; f < FT; ++f)
#pragma unroll
    for (int a = 0; a < AT; ++a) acc[f][a] = MFMA(Ag[f], Bg[a], acc[f][a]);
  __builtin_amdgcn_s_setprio(0);

  __syncthreads();  // all waves finished reading input region; safe to overwrite

  // epilogue: bias + silu -> fp16, write swizzled (2-way, free)
#pragma unroll
  for (int f = 0; f < FT; ++f) {
#pragma unroll
    for (int rg = 0; rg < 4; ++rg) {
      const int feat = n0 + f * 32 + rg * 8 + lh * 4;
      const f32x4 bv = *(const f32x4*)(bias + feat);
#pragma unroll
      for (int a = 0; a < AT; ++a) {
        half4 h;
#pragma unroll
        for (int r = 0; r < 4; ++r) h[r] = (_Float16)fast_silu(acc[f][a][rg * 4 + r] + bv[r]);
        const int row = a * 32 + lr;
        *(half4*)(Hb + row * POUT + ((feat * 2) ^ ((row & 31) << 4))) = h;
      }
    }
  }
}

extern "C" __global__ void __launch_bounds__(512, 4)
mlp_kernel(const float* __restrict__ X, const int* __restrict__ species,
           const _Float16* __restrict__ wt1, const float* __restrict__ b1,
           const _Float16* __restrict__ wt2, const float* __restrict__ b2,
           const _Float16* __restrict__ wt3, const float* __restrict__ b3,
           const _Float16* __restrict__ w4h, const float* __restrict__ b4,
           float* __restrict__ out, int natoms) {
  __shared__ __align__(16) char H[64 * 1024];
  const int tid = threadIdx.x;
  const int lane = tid & 63;
  const int wid = tid >> 6;  // 8 feature-slice waves
  const int ntiles = (natoms + 63) >> 6;
  const long gmax = (long)natoms - 1;

  // Anti-phase skew: the second resident block on each CU starts ~32k cycles
  // late (~1/3 of a tile period) so its MFMA phases land on the first
  // block's epilogue phases. Sleeping waves release all issue slots.
  if (blockIdx.x >= (gridDim.x >> 1)) {
#pragma unroll
    for (int i = 0; i < 4; ++i) __builtin_amdgcn_s_sleep(127);
  }

  for (int t = blockIdx.x; t < ntiles; t += gridDim.x) {
    const long abase = (long)t << 6;

    // ---- stage X[64x256] -> fp16 LDS, pitch 512B, swizzled ----
    {
      const int r = tid >> 3, cg = tid & 7;
      long g = abase + r;
      if (g > gmax) g = gmax;  // clamp: pad rows read a valid row, never stored
      const float* xp = X + g * 256;
      const int sw = (r & 31) << 4;
#pragma unroll
      for (int j = 0; j < 8; ++j) {
        const int colh = cg * 4 + j * 32;
        f32x4 v = *(const f32x4*)(xp + colh);
        half4 h;
#pragma unroll
        for (int e = 0; e < 4; ++e) h[e] = (_Float16)v[e];
        *(half4*)(H + r * 512 + ((colh * 2) ^ sw)) = h;
      }
    }
    __syncthreads();

    // ---- touch-prefetch next tile's X into L2/L3: one 128B line per thread
    // (512 threads x 128B = the full 64KB next tile). asm sink keeps the
    // load live without spending registers on the data (rule #17).
    {
      const long tn = (long)t + gridDim.x;
      if ((tn << 6) < (long)natoms) {
        long gp = (tn << 6) * 256 + tid * 32;
        const long gmaxf = (long)natoms * 256 - 1;
        if (gp > gmaxf) gp = gmaxf;
        float v = X[gp];
        asm volatile("" ::"v"(v));
      }
    }

    // L1: Xh[64x256] -> H1[64x512]   (8 wfeat x FT=2 -> 512 feats)
    layer<2, 2, 16, 512, 1024>(wt1, b1, H, wid, lane);
    __syncthreads();
    // L2: H1 -> H2[64x512]
    layer<2, 2, 32, 1024, 1024>(wt2, b2, H, wid, lane);
    __syncthreads();
    // L3: H2 -> H3[64x256]           (8 wfeat x FT=1 -> 256 feats)
    layer<1, 2, 32, 1024, 1024>(wt3, b3, H, wid, lane);
    __syncthreads();

    // L4: out[atom] = dot(H3[atom], w4) + b4, masked by species
    {
      const int atom = tid >> 3, part = tid & 7;
      const int sw = (atom & 31) << 4;
      const char* h3 = H + atom * 1024;
      const _Float16* w4p = w4h + part * 32;
      float sum = 0.0f;
#pragma unroll
      for (int j = 0; j < 4; ++j) {
        half8 h = *(const half8*)(h3 + ((part * 64 + j * 16) ^ sw));
        half8 w = *(const half8*)(w4p + j * 8);
#pragma unroll
        for (int e = 0; e < 8; ++e) sum += (float)h[e] * (float)w[e];
      }
      sum += __shfl_xor(sum, 1);
      sum += __shfl_xor(sum, 2);
      sum += __shfl_xor(sum, 4);
      if (part == 0) {
        const long g = abase + atom;
        if (g < natoms) {
          float r = sum + b4[0];
          out[g] = (species[g] >= 0) ? r : 0.0f;
        }
      }
    }
    __syncthreads();  // L4 reads H; next iteration's staging overwrites it
  }
}

extern "C" void kernel_launch(void* const* d_in, const int* in_sizes, int n_in,
                              void* d_out, int out_size, void* d_ws, size_t ws_size,
                              hipStream_t stream) {
  const float* X = (const float*)d_in[0];
  const int* species = (const int*)d_in[1];
  const float* W1 = (const float*)d_in[2];
  const float* b1 = (const float*)d_in[3];
  const float* W2 = (const float*)d_in[4];
  const float* b2 = (const float*)d_in[5];
  const float* W3 = (const float*)d_in[6];
  const float* b3 = (const float*)d_in[7];
  const float* W4 = (const float*)d_in[8];
  const float* b4 = (const float*)d_in[9];
  float* out = (float*)d_out;
  const int natoms = in_sizes[0] / 256;

  char* ws = (char*)d_ws;
  _Float16* wt1 = (_Float16*)(ws);                             // 512*256*2 B
  _Float16* wt2 = (_Float16*)(ws + 262144);                    // 512*512*2 B
  _Float16* wt3 = (_Float16*)(ws + 262144 + 524288);           // 256*512*2 B
  _Float16* w4h = (_Float16*)(ws + 262144 + 524288 + 262144);  // 512 B

  const int prep_total = 512 * 256 + 512 * 512 + 256 * 512 + 256;
  hipLaunchKernelGGL(prep_weights, dim3((prep_total + 255) / 256), dim3(256), 0, stream,
                     W1, W2, W3, W4, wt1, wt2, wt3, w4h);

  const int ntiles = (natoms + 63) / 64;
  const int nblocks = ntiles < 512 ? ntiles : 512;  // persistent: 2 blocks/CU
  hipLaunchKernelGGL(mlp_kernel, dim3(nblocks), dim3(512), 0, stream,
                     X, species, wt1, b1, wt2, b2, wt3, b3, w4h, b4, out, natoms);
}

// Round 2
// 395.762 us; speedup vs baseline: 1.2534x; 1.2534x over previous
//
#include <hip/hip_runtime.h>

typedef _Float16 half8 __attribute__((ext_vector_type(8)));
typedef _Float16 half4 __attribute__((ext_vector_type(4)));
typedef float f32x4 __attribute__((ext_vector_type(4)));
typedef float f32x16 __attribute__((ext_vector_type(16)));

// ---------------- prologue: cast + retile weights to fp16 MFMA tiles --------
// Tile (nb, ks): n in [nb*32,+32), k in [ks*16,+16), 512 halfs; lane l of a
// wave reads its A-fragment at tile_base + l*8 halfs (= l*16 bytes) -> one
// coalesced 1KB load. offset within tile for (lr=n&31, kk=k&15):
//   lr*8 + (kk>>3)*256 + (kk&7)   [halfs]
__global__ void prep_weights(const float* __restrict__ W1, const float* __restrict__ W2,
                             const float* __restrict__ W3, const float* __restrict__ W4,
                             _Float16* __restrict__ wt1, _Float16* __restrict__ wt2,
                             _Float16* __restrict__ wt3, _Float16* __restrict__ w4h) {
  int idx = blockIdx.x * blockDim.x + threadIdx.x;
  if (idx < 512 * 256) {  // W1: K=256, N=512, KS=16
    int k = idx >> 9, n = idx & 511;
    int off = (((n >> 5) * 16 + (k >> 4)) << 9) + (n & 31) * 8 + (((k >> 3) & 1) << 8) + (k & 7);
    wt1[off] = (_Float16)W1[idx];
    return;
  }
  int i2 = idx - 512 * 256;
  if (i2 < 512 * 512) {  // W2: K=512, N=512, KS=32
    int k = i2 >> 9, n = i2 & 511;
    int off = (((n >> 5) * 32 + (k >> 4)) << 9) + (n & 31) * 8 + (((k >> 3) & 1) << 8) + (k & 7);
    wt2[off] = (_Float16)W2[i2];
    return;
  }
  int i3 = i2 - 512 * 512;
  if (i3 < 512 * 256) {  // W3: K=512, N=256, KS=32
    int k = i3 >> 8, n = i3 & 255;
    int off = (((n >> 5) * 32 + (k >> 4)) << 9) + (n & 31) * 8 + (((k >> 3) & 1) << 8) + (k & 7);
    wt3[off] = (_Float16)W3[i3];
    return;
  }
  int i4 = i3 - 512 * 256;
  if (i4 < 256) w4h[i4] = (_Float16)W4[i4];
}

// silu with raw v_rcp_f32 (no IEEE div sequence); ~1ulp, well within tolerance
__device__ __forceinline__ float fast_silu(float s) {
  float e = __expf(-s);
  float d = 1.0f + e;
  float r;
  asm("v_rcp_f32 %0, %1" : "=v"(r) : "v"(d));
  return s * r;
}

// ---------------- fused MLP ----------------
// Block: 64 atoms, 512 threads = 8 waves (wave = feature slice).
// FT=2, AT=2: acc = 64 AGPR, arch-VGPR ~64 -> 4 waves/SIMD; LDS 64KB
// -> 2 blocks/CU -> 16 waves/CU.
// Swizzle (R8): byte ^= (row&31)<<4 — 5-bit XOR spreads a wave's 64 lanes
// over 32 distinct 16B slots (512B bank span) -> 2 lanes/bank = conflict-
// free. The old 3-bit mask collapsed to 8 slots -> ~8-way conflict, which
// made the LDS path dominate MFMA (R7: 3.1e7 conflict cycles).
// R9 FAILED (496us): persistent+skew+prefetch. Prefetch thrashed L2/L3
// (FETCH 181->560MB, WRITE 1.2->52MB). Reverted.
// R10 (this round): (1) bias folded into MFMA C-in (acc init = bias, loads
// transient, not held across K-loop); (2) silu computed IN-PLACE on acc
// BEFORE the mid-layer barrier — only the LDS stores need the barrier
// (they overwrite the H region other waves read); the silu VALU/trans
// chain now overlaps laggard waves' MFMA tails instead of serializing in
// the post-barrier critical section.

#define MFMA(a, b, c) __builtin_amdgcn_mfma_f32_32x32x16_f16(a, b, c, 0, 0, 0)

template <int FT, int AT, int KS, int PIN, int POUT>
__device__ __forceinline__ void layer(const _Float16* __restrict__ wt,
                                      const float* __restrict__ bias,
                                      char* __restrict__ Hb,
                                      int wfeat, int lane) {
  const int lr = lane & 31;
  const int lh = lane >> 5;
  const int n0 = wfeat * (FT * 32);
  const int s0 = (lr & 31) << 4;  // row swizzle; (a*32+lr)&31 == lr&31
  const char* Bp = Hb + lr * PIN;
  const char* wp = (const char*)wt + (size_t)(wfeat * FT * KS) * 1024 + lh * 512 + lr * 16;

  // init acc = bias (folds epilogue bias-add into MFMA C-in; bv transient)
  f32x16 acc[FT][AT];
#pragma unroll
  for (int f = 0; f < FT; ++f)
#pragma unroll
    for (int rg = 0; rg < 4; ++rg) {
      const int feat = n0 + f * 32 + rg * 8 + lh * 4;
      const f32x4 bv = *(const f32x4*)(bias + feat);
#pragma unroll
      for (int a = 0; a < AT; ++a)
#pragma unroll
        for (int r = 0; r < 4; ++r) acc[f][a][rg * 4 + r] = bv[r];
    }

  half8 Af[FT], Ag[FT], Bf[AT], Bg[AT];
#pragma unroll
  for (int f = 0; f < FT; ++f) Af[f] = *(const half8*)(wp + f * (KS * 1024));
#pragma unroll
  for (int a = 0; a < AT; ++a)
    Bf[a] = *(const half8*)(Bp + a * 32 * PIN + ((lh * 16) ^ s0));

#pragma unroll 1
  for (int ks = 0; ks < KS - 2; ks += 2) {
    // prefetch ks+1 into g-buffers
#pragma unroll
    for (int f = 0; f < FT; ++f)
      Ag[f] = *(const half8*)(wp + f * (KS * 1024) + (ks + 1) * 1024);
#pragma unroll
    for (int a = 0; a < AT; ++a)
      Bg[a] = *(const half8*)(Bp + a * 32 * PIN + (((ks + 1) * 32 + lh * 16) ^ s0));
    // compute ks
#pragma unroll
    for (int f = 0; f < FT; ++f)
#pragma unroll
      for (int a = 0; a < AT; ++a) acc[f][a] = MFMA(Af[f], Bf[a], acc[f][a]);
    // prefetch ks+2 into f-buffers
#pragma unroll
    for (int f = 0; f < FT; ++f)
      Af[f] = *(const half8*)(wp + f * (KS * 1024) + (ks + 2) * 1024);
#pragma unroll
    for (int a = 0; a < AT; ++a)
      Bf[a] = *(const half8*)(Bp + a * 32 * PIN + (((ks + 2) * 32 + lh * 16) ^ s0));
    // compute ks+1
#pragma unroll
    for (int f = 0; f < FT; ++f)
#pragma unroll
      for (int a = 0; a < AT; ++a) acc[f][a] = MFMA(Ag[f], Bg[a], acc[f][a]);
  }
  // tail: ks = KS-2 in f-buffers; prefetch KS-1; compute both
#pragma unroll
  for (int f = 0; f < FT; ++f)
    Ag[f] = *(const half8*)(wp + f * (KS * 1024) + (KS - 1) * 1024);
#pragma unroll
  for (int a = 0; a < AT; ++a)
    Bg[a] = *(const half8*)(Bp + a * 32 * PIN + ((((KS - 1) * 32) + lh * 16) ^ s0));
#pragma unroll
  for (int f = 0; f < FT; ++f)
#pragma unroll
    for (int a = 0; a < AT; ++a) acc[f][a] = MFMA(Af[f], Bf[a], acc[f][a]);
#pragma unroll
  for (int f = 0; f < FT; ++f)
#pragma unroll
    for (int a = 0; a < AT; ++a) acc[f][a] = MFMA(Ag[f], Bg[a], acc[f][a]);

  // silu in-place on private accumulators — BEFORE the barrier. Overlaps
  // laggard waves' MFMA tails; shrinks the post-barrier critical section
  // to cvt+store only. Zero extra sustained registers.
#pragma unroll
  for (int f = 0; f < FT; ++f)
#pragma unroll
    for (int a = 0; a < AT; ++a)
#pragma unroll
      for (int j = 0; j < 16; ++j) acc[f][a][j] = fast_silu(acc[f][a][j]);

  __syncthreads();  // all waves finished reading input region; safe to overwrite

  // post-barrier: cvt -> fp16, write swizzled (2-way, free)
#pragma unroll
  for (int f = 0; f < FT; ++f) {
#pragma unroll
    for (int rg = 0; rg < 4; ++rg) {
      const int feat = n0 + f * 32 + rg * 8 + lh * 4;
#pragma unroll
      for (int a = 0; a < AT; ++a) {
        half4 h;
#pragma unroll
        for (int r = 0; r < 4; ++r) h[r] = (_Float16)acc[f][a][rg * 4 + r];
        const int row = a * 32 + lr;
        *(half4*)(Hb + row * POUT + ((feat * 2) ^ ((row & 31) << 4))) = h;
      }
    }
  }
}

extern "C" __global__ void __launch_bounds__(512, 4)
mlp_kernel(const float* __restrict__ X, const int* __restrict__ species,
           const _Float16* __restrict__ wt1, const float* __restrict__ b1,
           const _Float16* __restrict__ wt2, const float* __restrict__ b2,
           const _Float16* __restrict__ wt3, const float* __restrict__ b3,
           const _Float16* __restrict__ w4h, const float* __restrict__ b4,
           float* __restrict__ out, int natoms) {
  __shared__ __align__(16) char H[64 * 1024];
  const int tid = threadIdx.x;
  const int lane = tid & 63;
  const int wid = tid >> 6;  // 8 feature-slice waves
  const long abase = (long)blockIdx.x * 64;

  // ---- stage X[64x256] -> fp16 LDS, pitch 512B, swizzled ----
  {
    const int r = tid >> 3, cg = tid & 7;
    long g = abase + r;
    const long gmax = (long)natoms - 1;
    if (g > gmax) g = gmax;  // clamp: pad rows read a valid row, never stored
    const float* xp = X + g * 256;
    const int sw = (r & 31) << 4;
#pragma unroll
    for (int j = 0; j < 8; ++j) {
      const int colh = cg * 4 + j * 32;
      f32x4 v = *(const f32x4*)(xp + colh);
      half4 h;
#pragma unroll
      for (int e = 0; e < 4; ++e) h[e] = (_Float16)v[e];
      *(half4*)(H + r * 512 + ((colh * 2) ^ sw)) = h;
    }
  }
  __syncthreads();

  // L1: Xh[64x256] -> H1[64x512]   (8 wfeat x FT=2 -> 512 feats)
  layer<2, 2, 16, 512, 1024>(wt1, b1, H, wid, lane);
  __syncthreads();
  // L2: H1 -> H2[64x512]
  layer<2, 2, 32, 1024, 1024>(wt2, b2, H, wid, lane);
  __syncthreads();
  // L3: H2 -> H3[64x256]           (8 wfeat x FT=1 -> 256 feats)
  layer<1, 2, 32, 1024, 1024>(wt3, b3, H, wid, lane);
  __syncthreads();

  // L4: out[atom] = dot(H3[atom], w4) + b4, masked by species
  const int atom = tid >> 3, part = tid & 7;
  const int sw = (atom & 31) << 4;
  const char* h3 = H + atom * 1024;
  const _Float16* w4p = w4h + part * 32;
  float sum = 0.0f;
#pragma unroll
  for (int j = 0; j < 4; ++j) {
    half8 h = *(const half8*)(h3 + ((part * 64 + j * 16) ^ sw));
    half8 w = *(const half8*)(w4p + j * 8);
#pragma unroll
    for (int e = 0; e < 8; ++e) sum += (float)h[e] * (float)w[e];
  }
  sum += __shfl_xor(sum, 1);
  sum += __shfl_xor(sum, 2);
  sum += __shfl_xor(sum, 4);
  if (part == 0) {
    const long g = abase + atom;
    if (g < natoms) {
      float r = sum + b4[0];
      out[g] = (species[g] >= 0) ? r : 0.0f;
    }
  }
}

extern "C" void kernel_launch(void* const* d_in, const int* in_sizes, int n_in,
                              void* d_out, int out_size, void* d_ws, size_t ws_size,
                              hipStream_t stream) {
  const float* X = (const float*)d_in[0];
  const int* species = (const int*)d_in[1];
  const float* W1 = (const float*)d_in[2];
  const float* b1 = (const float*)d_in[3];
  const float* W2 = (const float*)d_in[4];
  const float* b2 = (const float*)d_in[5];
  const float* W3 = (const float*)d_in[6];
  const float* b3 = (const float*)d_in[7];
  const float* W4 = (const float*)d_in[8];
  const float* b4 = (const float*)d_in[9];
  float* out = (float*)d_out;
  const int natoms = in_sizes[0] / 256;

  char* ws = (char*)d_ws;
  _Float16* wt1 = (_Float16*)(ws);                             // 512*256*2 B
  _Float16* wt2 = (_Float16*)(ws + 262144);                    // 512*512*2 B
  _Float16* wt3 = (_Float16*)(ws + 262144 + 524288);           // 256*512*2 B
  _Float16* w4h = (_Float16*)(ws + 262144 + 524288 + 262144);  // 512 B

  const int prep_total = 512 * 256 + 512 * 512 + 256 * 512 + 256;
  hipLaunchKernelGGL(prep_weights, dim3((prep_total + 255) / 256), dim3(256), 0, stream,
                     W1, W2, W3, W4, wt1, wt2, wt3, w4h);

  const int nblocks = (natoms + 63) / 64;
  hipLaunchKernelGGL(mlp_kernel, dim3(nblocks), dim3(512), 0, stream,
                     X, species, wt1, b1, wt2, b2, wt3, b3, w4h, b4, out, natoms);
}